// Round 11
// baseline (120.306 us; speedup 1.0000x reference)
//
#include <hip/hip_runtime.h>
#include <hip/hip_bf16.h>

// GPT-2 attention block: B=2, S=2048, D=768, H=12, hd=64
#define BATCH 2
#define SEQ   2048
#define DMODEL 768
#define NHEAD 12
#define HDIM  64
#define QKVD  2304   // 3*DMODEL

typedef __bf16 bf16x8 __attribute__((ext_vector_type(8)));
typedef float f32x4 __attribute__((ext_vector_type(4)));
typedef float f32x16 __attribute__((ext_vector_type(16)));

static __device__ inline f32x4 mfma16(bf16x8 a, bf16x8 b, f32x4 c) {
    return __builtin_amdgcn_mfma_f32_16x16x32_bf16(a, b, c, 0, 0, 0);
}
static __device__ inline f32x16 mfma32(bf16x8 a, bf16x8 b, f32x16 c) {
    return __builtin_amdgcn_mfma_f32_32x32x16_bf16(a, b, c, 0, 0, 0);
}

static __device__ inline unsigned short f2bf_bits(float f) {
    __hip_bfloat16 h = __float2bfloat16(f);
    return __builtin_bit_cast(unsigned short, h);
}
static __device__ inline unsigned int pack_bf16(float a, float b) {
    return (unsigned int)f2bf_bits(a) | ((unsigned int)f2bf_bits(b) << 16);
}

// async global->LDS, 16B per lane
static __device__ inline void gload16(const __hip_bfloat16* g, __hip_bfloat16* l) {
    __builtin_amdgcn_global_load_lds(
        (const __attribute__((address_space(1))) void*)g,
        (__attribute__((address_space(3))) void*)l, 16, 0, 0);
}

// ---------------- conversion kernels ----------------

__global__ __launch_bounds__(256) void f32_to_bf16_k(const float* __restrict__ in,
                                                     __hip_bfloat16* __restrict__ out) {
    int i = blockIdx.x * 256 + threadIdx.x;
    float4 v = reinterpret_cast<const float4*>(in)[i];
    ushort4 o;
    o.x = f2bf_bits(v.x); o.y = f2bf_bits(v.y);
    o.z = f2bf_bits(v.z); o.w = f2bf_bits(v.w);
    reinterpret_cast<ushort4*>(out)[i] = o;
}

__global__ __launch_bounds__(256) void transpose_f32_to_bf16(const float* __restrict__ in,
                                                             __hip_bfloat16* __restrict__ out,
                                                             int R, int C) {
    __shared__ float t[32][33];
    int tx = threadIdx.x & 31, ty = threadIdx.x >> 5;
    int bx = blockIdx.x * 32;
    int by = blockIdx.y * 32;
#pragma unroll
    for (int k = 0; k < 4; k++)
        t[ty + k * 8][tx] = in[(size_t)(by + ty + k * 8) * C + bx + tx];
    __syncthreads();
#pragma unroll
    for (int k = 0; k < 4; k++)
        out[(size_t)(bx + ty + k * 8) * R + by + tx] = __float2bfloat16(t[tx][ty + k * 8]);
}

// V slice of QKV -> VT[bh][d][token]  (bf16, LDS-tiled, coalesced both sides)
__global__ __launch_bounds__(256) void transpose_v(const __hip_bfloat16* __restrict__ qkv,
                                                   __hip_bfloat16* __restrict__ VT) {
    __shared__ __hip_bfloat16 t[32][33];
    int tx = threadIdx.x & 31, ty = threadIdx.x >> 5;  // 32 x 8
    int tok0 = blockIdx.x * 32;
    int bd = blockIdx.y;            // bh*2 + dhalf
    int bh = bd >> 1;
    int d0 = (bd & 1) * 32;
    int b = bh / NHEAD, h = bh - (bh / NHEAD) * NHEAD;
    const __hip_bfloat16* src = qkv + (size_t)(b * SEQ + tok0) * QKVD + 2 * DMODEL + h * HDIM + d0;
#pragma unroll
    for (int k = 0; k < 4; k++)
        t[ty + k * 8][tx] = src[(size_t)(ty + k * 8) * QKVD + tx];    // [token][d]
    __syncthreads();
    __hip_bfloat16* dst = VT + (size_t)bh * HDIM * SEQ + (size_t)d0 * SEQ + tok0;
#pragma unroll
    for (int k = 0; k < 4; k++)
        dst[(size_t)(ty + k * 8) * SEQ + tx] = t[tx][ty + k * 8];     // [d][token]
}

// ---------------- GEMM v2: single-barrier double-buffered staging (unchanged) ----------------

template <bool OUT_BF16>
__global__ __launch_bounds__(256) void gemm_bt(const __hip_bfloat16* __restrict__ A,
                                               const __hip_bfloat16* __restrict__ Bt,
                                               const float* __restrict__ bias,
                                               void* __restrict__ Cp,
                                               int M, int N, int K) {
    __shared__ __hip_bfloat16 Al[2][128 * 32];
    __shared__ __hip_bfloat16 Bl[2][128 * 32];

    int tid = threadIdx.x;
    int wid = tid >> 6;
    int lane = tid & 63;
    int lr = lane & 15;
    int lg = lane >> 4;
    int m0 = blockIdx.y * 128;
    int n0 = blockIdx.x * 128;
    int wm = (wid >> 1) * 64;
    int wn = (wid & 1) * 64;

    int srow = wid * 16 + (lane >> 2);
    int scol = (lane & 3) * 8;
    const __hip_bfloat16* ag = A + (size_t)(m0 + srow) * K + scol;
    const __hip_bfloat16* bg = Bt + (size_t)(n0 + srow) * K + scol;
    int lofs = wid * 512;

    f32x4 acc[4][4] = {};

    gload16(ag, &Al[0][lofs]);
    gload16(ag + (size_t)64 * K, &Al[0][lofs + 2048]);
    gload16(bg, &Bl[0][lofs]);
    gload16(bg + (size_t)64 * K, &Bl[0][lofs + 2048]);
    __syncthreads();

    int nk = K >> 5;
    for (int t = 0; t < nk; t++) {
        int cb = t & 1;
        if (t + 1 < nk) {
            int k0 = (t + 1) << 5;
            int nb = cb ^ 1;
            gload16(ag + k0, &Al[nb][lofs]);
            gload16(ag + (size_t)64 * K + k0, &Al[nb][lofs + 2048]);
            gload16(bg + k0, &Bl[nb][lofs]);
            gload16(bg + (size_t)64 * K + k0, &Bl[nb][lofs + 2048]);
        }

        bf16x8 af[4], bfr[4];
#pragma unroll
        for (int i = 0; i < 4; i++)
            af[i] = *reinterpret_cast<const bf16x8*>(&Al[cb][(wm + i * 16 + lr) * 32 + lg * 8]);
#pragma unroll
        for (int j = 0; j < 4; j++)
            bfr[j] = *reinterpret_cast<const bf16x8*>(&Bl[cb][(wn + j * 16 + lr) * 32 + lg * 8]);
#pragma unroll
        for (int i = 0; i < 4; i++)
#pragma unroll
            for (int j = 0; j < 4; j++)
                acc[i][j] = mfma16(af[i], bfr[j], acc[i][j]);
        __syncthreads();
    }

#pragma unroll
    for (int i = 0; i < 4; i++) {
#pragma unroll
        for (int j = 0; j < 4; j++) {
            int col = n0 + wn + j * 16 + lr;
            float bv = bias[col];
#pragma unroll
            for (int r = 0; r < 4; r++) {
                int row = m0 + wm + i * 16 + lg * 4 + r;
                float v = acc[i][j][r] + bv;
                if (OUT_BF16)
                    ((__hip_bfloat16*)Cp)[(size_t)row * N + col] = __float2bfloat16(v);
                else
                    ((float*)Cp)[(size_t)row * N + col] = v;
            }
        }
    }
}

// ---------------- causal flash attention v11: zero-LDS main loop via global V^T ----------------
// grid 1536 = 24 bh x 64 q-tiles (largest first, XCD-chunked), block 256 = 4 waves.
// Wave w owns kv quarter [128t+32w, +32). V^T pre-transposed to global VT[bh][d][kv]:
// PV A-fragments are single bf16x8 loads (contiguous along kv, L2-resident) -- NO LDS,
// NO staging VALU in the loop. K frags reg-reloaded from L2. In-register P repack
// (4 shfl), T13 defer-max, setprio on MFMA. Barrier-free loop; end: 4-way combine.

#define KS2 0.18033688f  // 0.125 * log2(e)

__global__ __launch_bounds__(256, 3) void flash_attn(const __hip_bfloat16* __restrict__ qkv,
                                                     const __hip_bfloat16* __restrict__ VT,
                                                     __hip_bfloat16* __restrict__ attn_out) {
    // combine-only LDS: SC_w (w=1..3) at (w-1)*8448; OL at 25344 ([32 q][72 d] bf16)
    __shared__ __align__(16) char smem[30208];

    int tid = threadIdx.x;
    int w = tid >> 6;        // wave = kv quarter
    int lane = tid & 63;
    int l31 = lane & 31;
    int lg2 = lane >> 5;

    // block -> (xcd-chunked head, descending q-tile)
    int wg = blockIdx.x;
    int xcd = wg & 7;
    int slot = wg >> 3;          // 0..191
    int hsl = slot % 3;
    int qsl = slot / 3;          // 0..63
    int bh = xcd * 3 + hsl;
    int it = 63 - qsl;           // largest first
    int b = bh / NHEAD;
    int h = bh - b * NHEAD;
    int q0 = it * 32;
    int bbase = b * SEQ;

    // per-wave iteration count: kv quarters 32*(4t+w) <= q0
    int Tw = (it >= w) ? ((it - w) >> 2) + 1 : 0;

    const __hip_bfloat16* Kg = qkv + (size_t)bbase * QKVD + DMODEL + h * HDIM;
    const __hip_bfloat16* VTh = VT + (size_t)bh * HDIM * SEQ;

    // Q fragments (B operand: col=q=l31, k=d)
    const __hip_bfloat16* qg = qkv + (size_t)(bbase + q0 + l31) * QKVD + h * HDIM;
    bf16x8 qf[4];
#pragma unroll
    for (int kd = 0; kd < 4; kd++)
        qf[kd] = *reinterpret_cast<const bf16x8*>(qg + kd * 16 + lg2 * 8);

    f32x16 o0 = {}, o1 = {};
    float m = -3.0e38f, l = 0.f;

    bf16x8 kc[4];
    // prologue: K fragments for tile 0
    {
        const __hip_bfloat16* kr = Kg + (size_t)(32 * w + l31) * QKVD;
#pragma unroll
        for (int kd = 0; kd < 4; kd++)
            kc[kd] = *reinterpret_cast<const bf16x8*>(kr + kd * 16 + lg2 * 8);
    }

    for (int t = 0; t < Tw; t++) {
        int kvbase = 128 * t + 32 * w;
        bool hn = (t + 1 < Tw);

        // ---- issue V^T fragment loads early (consumed by PV; hidden under QK+softmax) ----
        bf16x8 vf[4];
#pragma unroll
        for (int ks = 0; ks < 2; ks++)
#pragma unroll
            for (int dh = 0; dh < 2; dh++)
                vf[ks * 2 + dh] = *reinterpret_cast<const bf16x8*>(
                    VTh + (size_t)(dh * 32 + l31) * SEQ + kvbase + ks * 16 + lg2 * 8);

        // ---- S^T = mfma32(K, Q): col=q=l31, row kv_local=(j&3)+8*(j>>2)+4*lg2 ----
        __builtin_amdgcn_s_setprio(1);
        f32x16 st = {};
#pragma unroll
        for (int kd = 0; kd < 4; kd++)
            st = mfma32(kc[kd], qf[kd], st);
        __builtin_amdgcn_s_setprio(0);

        if (hn) {  // kc consumed: reload for next tile (L2-resident)
            const __hip_bfloat16* kr = Kg + (size_t)(kvbase + 128 + l31) * QKVD;
#pragma unroll
            for (int kd = 0; kd < 4; kd++)
                kc[kd] = *reinterpret_cast<const bf16x8*>(kr + kd * 16 + lg2 * 8);
        }

        if (kvbase == q0) {  // diagonal subtile: causal mask
#pragma unroll
            for (int j = 0; j < 16; j++) {
                int kvl = (j & 3) + 8 * (j >> 2) + 4 * lg2;
                if (kvl > l31) st[j] = -3.0e38f;
            }
        }
        // ---- online softmax (per-lane q=l31; halves merged via shfl 32) ----
        float tm[16];
#pragma unroll
        for (int j = 0; j < 16; j++) tm[j] = st[j];
#pragma unroll
        for (int dd = 8; dd >= 1; dd >>= 1)
#pragma unroll
            for (int j = 0; j < 8; j++)
                if (j < dd) tm[j] = fmaxf(tm[j], tm[j + dd]);
        float mx = fmaxf(tm[0], __shfl_xor(tm[0], 32, 64));
        bool small = __all(mx <= m + 44.0f);  // T13 defer-max
        float mnew = small ? m : fmaxf(m, mx);
#pragma unroll
        for (int j = 0; j < 16; j++)
            st[j] = __builtin_amdgcn_exp2f((st[j] - mnew) * KS2);
        float ts[16];
#pragma unroll
        for (int j = 0; j < 16; j++) ts[j] = st[j];
#pragma unroll
        for (int dd = 8; dd >= 1; dd >>= 1)
#pragma unroll
            for (int j = 0; j < 8; j++)
                if (j < dd) ts[j] += ts[j + dd];
        float ls = ts[0] + __shfl_xor(ts[0], 32, 64);
        if (small) {
            l += ls;
        } else {
            float sc = __builtin_amdgcn_exp2f((m - mnew) * KS2);
            l = l * sc + ls;
            o0 *= sc;
            o1 *= sc;
            m = mnew;
        }

        // ---- in-register P repack (4 shfl) + PV from global V^T fragments ----
#pragma unroll
        for (int ks = 0; ks < 2; ks++) {
            unsigned int a0 = pack_bf16(st[8 * ks + 0], st[8 * ks + 1]);
            unsigned int a1 = pack_bf16(st[8 * ks + 2], st[8 * ks + 3]);
            unsigned int b0 = pack_bf16(st[8 * ks + 4], st[8 * ks + 5]);
            unsigned int b1 = pack_bf16(st[8 * ks + 6], st[8 * ks + 7]);
            unsigned int y0 = lg2 ? a0 : b0;
            unsigned int y1 = lg2 ? a1 : b1;
            unsigned int p0 = __shfl_xor(y0, 32, 64);
            unsigned int p1 = __shfl_xor(y1, 32, 64);
            union { unsigned int u[4]; bf16x8 v; } pf;
            pf.u[0] = lg2 ? p0 : a0;
            pf.u[1] = lg2 ? p1 : a1;
            pf.u[2] = lg2 ? b0 : p0;
            pf.u[3] = lg2 ? b1 : p1;
            __builtin_amdgcn_s_setprio(1);
            o0 = mfma32(vf[ks * 2 + 0], pf.v, o0);
            o1 = mfma32(vf[ks * 2 + 1], pf.v, o1);
            __builtin_amdgcn_s_setprio(0);
        }
    }

    __syncthreads();  // waves done before combine staging

    // ---- 4-way combine: waves 1..3 stage (o,m,l); wave 0 merges ----
    if (w != 0) {
        float* SCw = (float*)(smem + (w - 1) * 8448);
#pragma unroll
        for (int j = 0; j < 16; j++) {
            int dl = (j & 3) + 8 * (j >> 2) + 4 * lg2;
            SCw[dl * 32 + l31] = o0[j];
            SCw[(32 + dl) * 32 + l31] = o1[j];
        }
        if (lg2 == 0) {
            SCw[2048 + l31] = m;
            SCw[2048 + 32 + l31] = l;
        }
    }
    __syncthreads();
    if (w == 0) {
        float* SC1 = (float*)(smem + 0);
        float* SC2 = (float*)(smem + 8448);
        float* SC3 = (float*)(smem + 16896);
        __hip_bfloat16* OL = (__hip_bfloat16*)(smem + 25344);
        float m1 = SC1[2048 + l31], l1 = SC1[2048 + 32 + l31];
        float m2 = SC2[2048 + l31], l2 = SC2[2048 + 32 + l31];
        float m3 = SC3[2048 + l31], l3 = SC3[2048 + 32 + l31];
        float M = fmaxf(fmaxf(m, m1), fmaxf(m2, m3));
        float e0 = __builtin_amdgcn_exp2f((m - M) * KS2);
        float e1 = __builtin_amdgcn_exp2f((m1 - M) * KS2);
        float e2 = __builtin_amdgcn_exp2f((m2 - M) * KS2);
        float e3 = __builtin_amdgcn_exp2f((m3 - M) * KS2);
        float L = l * e0 + l1 * e1 + l2 * e2 + l3 * e3;
        float linv = 1.0f / L;
#pragma unroll
        for (int od = 0; od < 2; od++) {
#pragma unroll
            for (int g = 0; g < 4; g++) {
                int dbase = od * 32 + 8 * g + 4 * lg2;
                ushort4 w4;
#pragma unroll
                for (int r = 0; r < 4; r++) {
                    int d = dbase + r;
                    float self = od ? o1[4 * g + r] : o0[4 * g + r];
                    float v = self * e0 + SC1[d * 32 + l31] * e1 +
                              SC2[d * 32 + l31] * e2 + SC3[d * 32 + l31] * e3;
                    v *= linv;
                    ((unsigned short*)&w4)[r] = f2bf_bits(v);
                }
                *reinterpret_cast<ushort4*>(&OL[l31 * 72 + dbase]) = w4;
            }
        }
    }
    __syncthreads();
    // coalesced store: 256 threads cover 32 q x 64 d
    {
        __hip_bfloat16* OL = (__hip_bfloat16*)(smem + 25344);
        int r = tid >> 3, c = (tid & 7) * 8;
        __hip_bfloat16* dst = attn_out + (size_t)(bbase + q0 + r) * DMODEL + h * HDIM + c;
        *reinterpret_cast<uint4*>(dst) = *reinterpret_cast<const uint4*>(&OL[r * 72 + c]);
    }
}

// ---------------- launch ----------------

extern "C" void kernel_launch(void* const* d_in, const int* in_sizes, int n_in,
                              void* d_out, int out_size, void* d_ws, size_t ws_size,
                              hipStream_t stream) {
    const float* hidden = (const float*)d_in[0];   // [2,2048,768]
    const float* w_attn = (const float*)d_in[1];   // [768,2304]
    const float* b_attn = (const float*)d_in[2];   // [2304]
    const float* w_proj = (const float*)d_in[3];   // [768,768]
    const float* b_proj = (const float*)d_in[4];   // [768]
    float* out = (float*)d_out;                    // [2,2048,768]

    char* ws = (char*)d_ws;
    __hip_bfloat16* Xb  = (__hip_bfloat16*)(ws + 0);         // 4096*768*2 = 6291456
    __hip_bfloat16* Wta = (__hip_bfloat16*)(ws + 6291456);   // 2304*768*2
    __hip_bfloat16* Wtp = (__hip_bfloat16*)(ws + 9830400);   // 768*768*2
    __hip_bfloat16* QKV = (__hip_bfloat16*)(ws + 11010048);  // 4096*2304*2
    __hip_bfloat16* AO  = (__hip_bfloat16*)(ws + 29884416);  // 4096*768*2
    // VT aliases Xb (dead after QKV GEMM): 24*64*2048*2 = 6291456 bytes, exact fit
    __hip_bfloat16* VTb = (__hip_bfloat16*)(ws + 0);

    const int M = BATCH * SEQ;  // 4096

    f32_to_bf16_k<<<dim3(M * DMODEL / (256 * 4)), dim3(256), 0, stream>>>(hidden, Xb);
    transpose_f32_to_bf16<<<dim3(QKVD / 32, DMODEL / 32), dim3(256), 0, stream>>>(w_attn, Wta, DMODEL, QKVD);
    transpose_f32_to_bf16<<<dim3(DMODEL / 32, DMODEL / 32), dim3(256), 0, stream>>>(w_proj, Wtp, DMODEL, DMODEL);
    gemm_bt<true><<<dim3(QKVD / 128, M / 128), dim3(256), 0, stream>>>(Xb, Wta, b_attn, QKV, M, QKVD, DMODEL);
    transpose_v<<<dim3(SEQ / 32, BATCH * NHEAD * 2), dim3(256), 0, stream>>>(QKV, VTb);
    flash_attn<<<dim3(1536), dim3(256), 0, stream>>>(QKV, VTb, AO);
    gemm_bt<false><<<dim3(DMODEL / 128, M / 128), dim3(256), 0, stream>>>(AO, Wtp, b_proj, out, M, DMODEL, DMODEL);
}

// Round 12
// 94.397 us; speedup vs baseline: 1.2745x; 1.2745x over previous
//
#include <hip/hip_runtime.h>
#include <hip/hip_bf16.h>

// GPT-2 attention block: B=2, S=2048, D=768, H=12, hd=64
#define BATCH 2
#define SEQ   2048
#define DMODEL 768
#define NHEAD 12
#define HDIM  64
#define QKVD  2304   // 3*DMODEL

typedef __bf16 bf16x8 __attribute__((ext_vector_type(8)));
typedef float f32x4 __attribute__((ext_vector_type(4)));
typedef float f32x16 __attribute__((ext_vector_type(16)));

static __device__ inline f32x4 mfma16(bf16x8 a, bf16x8 b, f32x4 c) {
    return __builtin_amdgcn_mfma_f32_16x16x32_bf16(a, b, c, 0, 0, 0);
}
static __device__ inline f32x16 mfma32(bf16x8 a, bf16x8 b, f32x16 c) {
    return __builtin_amdgcn_mfma_f32_32x32x16_bf16(a, b, c, 0, 0, 0);
}

static __device__ inline unsigned short f2bf_bits(float f) {
    __hip_bfloat16 h = __float2bfloat16(f);
    return __builtin_bit_cast(unsigned short, h);
}
static __device__ inline unsigned int pack_bf16(float a, float b) {
    return (unsigned int)f2bf_bits(a) | ((unsigned int)f2bf_bits(b) << 16);
}

// async global->LDS, 16B per lane
static __device__ inline void gload16(const __hip_bfloat16* g, __hip_bfloat16* l) {
    __builtin_amdgcn_global_load_lds(
        (const __attribute__((address_space(1))) void*)g,
        (__attribute__((address_space(3))) void*)l, 16, 0, 0);
}

// ---------------- conversion kernels ----------------

__global__ __launch_bounds__(256) void f32_to_bf16_k(const float* __restrict__ in,
                                                     __hip_bfloat16* __restrict__ out) {
    int i = blockIdx.x * 256 + threadIdx.x;
    float4 v = reinterpret_cast<const float4*>(in)[i];
    ushort4 o;
    o.x = f2bf_bits(v.x); o.y = f2bf_bits(v.y);
    o.z = f2bf_bits(v.z); o.w = f2bf_bits(v.w);
    reinterpret_cast<ushort4*>(out)[i] = o;
}

__global__ __launch_bounds__(256) void transpose_f32_to_bf16(const float* __restrict__ in,
                                                             __hip_bfloat16* __restrict__ out,
                                                             int R, int C) {
    __shared__ float t[32][33];
    int tx = threadIdx.x & 31, ty = threadIdx.x >> 5;
    int bx = blockIdx.x * 32;
    int by = blockIdx.y * 32;
#pragma unroll
    for (int k = 0; k < 4; k++)
        t[ty + k * 8][tx] = in[(size_t)(by + ty + k * 8) * C + bx + tx];
    __syncthreads();
#pragma unroll
    for (int k = 0; k < 4; k++)
        out[(size_t)(bx + ty + k * 8) * R + by + tx] = __float2bfloat16(t[tx][ty + k * 8]);
}

// ---------------- pack K,V into MFMA fragment order ----------------
// Kp[bh][q32][t*8..]: t=(kd*2+lg2)*32+l31 holds K[32*q32+l31][kd*16+lg2*8 .. +8]
// Vp[bh][q32][t*8..]: t=((ks*2+dh)*2+lg2)*32+l31 holds V^T[dh*32+l31][32*q32+ks*16+lg2*8 ..]
// One block per (q32, bh); coalesced global reads via LDS tile; coalesced 16B writes.

__global__ __launch_bounds__(256) void pack_kv(const __hip_bfloat16* __restrict__ qkv,
                                               __hip_bfloat16* __restrict__ Kp,
                                               __hip_bfloat16* __restrict__ Vp) {
    __shared__ __hip_bfloat16 Kl[32][72];
    __shared__ __hip_bfloat16 Vl[32][72];
    int tid = threadIdx.x;
    int q32 = blockIdx.x;            // 0..63
    int bh = blockIdx.y;             // 0..23
    int b = bh / NHEAD, h = bh - (bh / NHEAD) * NHEAD;
    int row = tid >> 3, cc = (tid & 7) * 8;
    const __hip_bfloat16* src = qkv + (size_t)(b * SEQ + q32 * 32 + row) * QKVD + h * HDIM + cc;
    *reinterpret_cast<uint4*>(&Kl[row][cc]) = *reinterpret_cast<const uint4*>(src + DMODEL);
    *reinterpret_cast<uint4*>(&Vl[row][cc]) = *reinterpret_cast<const uint4*>(src + 2 * DMODEL);
    __syncthreads();

    int l31 = tid & 31, half = (tid >> 5) & 1;
    size_t obase = (size_t)bh * 131072 + (size_t)q32 * 2048 + (size_t)tid * 8;

    // K fragment: contiguous 16B LDS read
    int kd = tid >> 6;
    bf16x8 kf = *reinterpret_cast<const bf16x8*>(&Kl[l31][kd * 16 + half * 8]);
    *reinterpret_cast<bf16x8*>(Kp + obase) = kf;

    // V fragment: column gather from LDS
    int ks = tid >> 7, dh = (tid >> 6) & 1;
    union { unsigned short s[8]; bf16x8 v; } vf;
#pragma unroll
    for (int i = 0; i < 8; i++)
        vf.s[i] = __builtin_bit_cast(unsigned short, Vl[ks * 16 + half * 8 + i][dh * 32 + l31]);
    *reinterpret_cast<bf16x8*>(Vp + obase) = vf.v;
}

// ---------------- GEMM: single-barrier double-buffered staging, strided-A ----------------

template <bool OUT_BF16>
__global__ __launch_bounds__(256) void gemm_bt(const __hip_bfloat16* __restrict__ A,
                                               const __hip_bfloat16* __restrict__ Bt,
                                               const float* __restrict__ bias,
                                               void* __restrict__ Cp,
                                               int M, int N, int K, int lda) {
    __shared__ __hip_bfloat16 Al[2][128 * 32];
    __shared__ __hip_bfloat16 Bl[2][128 * 32];

    int tid = threadIdx.x;
    int wid = tid >> 6;
    int lane = tid & 63;
    int lr = lane & 15;
    int lg = lane >> 4;
    int m0 = blockIdx.y * 128;
    int n0 = blockIdx.x * 128;
    int wm = (wid >> 1) * 64;
    int wn = (wid & 1) * 64;

    int srow = wid * 16 + (lane >> 2);
    int scol = (lane & 3) * 8;
    const __hip_bfloat16* ag = A + (size_t)(m0 + srow) * lda + scol;
    const __hip_bfloat16* bg = Bt + (size_t)(n0 + srow) * K + scol;
    int lofs = wid * 512;

    f32x4 acc[4][4] = {};

    gload16(ag, &Al[0][lofs]);
    gload16(ag + (size_t)64 * lda, &Al[0][lofs + 2048]);
    gload16(bg, &Bl[0][lofs]);
    gload16(bg + (size_t)64 * K, &Bl[0][lofs + 2048]);
    __syncthreads();

    int nk = K >> 5;
    for (int t = 0; t < nk; t++) {
        int cb = t & 1;
        if (t + 1 < nk) {
            int k0 = (t + 1) << 5;
            int nb = cb ^ 1;
            gload16(ag + k0, &Al[nb][lofs]);
            gload16(ag + (size_t)64 * lda + k0, &Al[nb][lofs + 2048]);
            gload16(bg + k0, &Bl[nb][lofs]);
            gload16(bg + (size_t)64 * K + k0, &Bl[nb][lofs + 2048]);
        }

        bf16x8 af[4], bfr[4];
#pragma unroll
        for (int i = 0; i < 4; i++)
            af[i] = *reinterpret_cast<const bf16x8*>(&Al[cb][(wm + i * 16 + lr) * 32 + lg * 8]);
#pragma unroll
        for (int j = 0; j < 4; j++)
            bfr[j] = *reinterpret_cast<const bf16x8*>(&Bl[cb][(wn + j * 16 + lr) * 32 + lg * 8]);
#pragma unroll
        for (int i = 0; i < 4; i++)
#pragma unroll
            for (int j = 0; j < 4; j++)
                acc[i][j] = mfma16(af[i], bfr[j], acc[i][j]);
        __syncthreads();
    }

#pragma unroll
    for (int i = 0; i < 4; i++) {
#pragma unroll
        for (int j = 0; j < 4; j++) {
            int col = n0 + wn + j * 16 + lr;
            float bv = bias[col];
#pragma unroll
            for (int r = 0; r < 4; r++) {
                int row = m0 + wm + i * 16 + lg * 4 + r;
                float v = acc[i][j][r] + bv;
                if (OUT_BF16)
                    ((__hip_bfloat16*)Cp)[(size_t)row * N + col] = __float2bfloat16(v);
                else
                    ((float*)Cp)[(size_t)row * N + col] = v;
            }
        }
    }
}

// ---------------- causal flash attention v12: coalesced packed-fragment loads ----------------
// grid 1536 = 24 bh x 64 q-tiles (largest first, XCD-chunked), block 256 = 4 waves.
// Wave w owns kv quarter qi=4t+w. K and V fragments read from packed Kp/Vp: every load
// is a fully-coalesced 1KB wave-load (16B/lane, contiguous) -- 8KB/iter L2 traffic, all
// useful (was 24KB). No LDS, no barriers in loop. In-register P repack (4 shfl),
// T13 defer-max, setprio. O written to the dead K-column hole of QKV (stride QKVD).

#define KS2 0.18033688f  // 0.125 * log2(e)

__global__ __launch_bounds__(256, 4) void flash_attn(const __hip_bfloat16* __restrict__ qkv,
                                                     const __hip_bfloat16* __restrict__ Kp,
                                                     const __hip_bfloat16* __restrict__ Vp,
                                                     __hip_bfloat16* __restrict__ obase) {
    // combine-only LDS: SC_w (w=1..3) at (w-1)*8448; OL at 25344 ([32 q][72 d] bf16)
    __shared__ __align__(16) char smem[30208];

    int tid = threadIdx.x;
    int w = tid >> 6;        // wave = kv quarter parity
    int lane = tid & 63;
    int l31 = lane & 31;
    int lg2 = lane >> 5;

    // block -> (xcd-chunked head, descending q-tile)
    int wg = blockIdx.x;
    int xcd = wg & 7;
    int slot = wg >> 3;          // 0..191
    int hsl = slot % 3;
    int qsl = slot / 3;          // 0..63
    int bh = xcd * 3 + hsl;
    int it = 63 - qsl;           // largest first
    int b = bh / NHEAD;
    int h = bh - b * NHEAD;
    int q0 = it * 32;
    int bbase = b * SEQ;

    // per-wave iteration count: kv quarters 32*(4t+w) <= q0
    int Tw = (it >= w) ? ((it - w) >> 2) + 1 : 0;

    const __hip_bfloat16* Kph = Kp + (size_t)bh * 131072;
    const __hip_bfloat16* Vph = Vp + (size_t)bh * 131072;

    // Q fragments (B operand: col=q=l31, k=d)
    const __hip_bfloat16* qg = qkv + (size_t)(bbase + q0 + l31) * QKVD + h * HDIM;
    bf16x8 qf[4];
#pragma unroll
    for (int kd = 0; kd < 4; kd++)
        qf[kd] = *reinterpret_cast<const bf16x8*>(qg + kd * 16 + lg2 * 8);

    f32x16 o0 = {}, o1 = {};
    float m = -3.0e38f, l = 0.f;

    bf16x8 kc[4];
    // prologue: K fragments for quarter qi=w (coalesced)
    {
        const __hip_bfloat16* kr = Kph + (size_t)w * 2048 + l31 * 8;
#pragma unroll
        for (int kd = 0; kd < 4; kd++)
            kc[kd] = *reinterpret_cast<const bf16x8*>(kr + (kd * 2 + lg2) * 256);
    }

    for (int t = 0; t < Tw; t++) {
        int qi = 4 * t + w;
        int kvbase = qi * 32;
        bool hn = (t + 1 < Tw);

        // ---- V^T fragments: coalesced packed loads, issued early ----
        const __hip_bfloat16* vr = Vph + (size_t)qi * 2048 + lg2 * 256 + l31 * 8;
        bf16x8 vf[4];
#pragma unroll
        for (int ks = 0; ks < 2; ks++)
#pragma unroll
            for (int dh = 0; dh < 2; dh++)
                vf[ks * 2 + dh] = *reinterpret_cast<const bf16x8*>(vr + (ks * 2 + dh) * 512);

        // ---- S^T = mfma32(K, Q): col=q=l31, row kv_local=(j&3)+8*(j>>2)+4*lg2 ----
        __builtin_amdgcn_s_setprio(1);
        f32x16 st = {};
#pragma unroll
        for (int kd = 0; kd < 4; kd++)
            st = mfma32(kc[kd], qf[kd], st);
        __builtin_amdgcn_s_setprio(0);

        if (hn) {  // kc consumed: reload next quarter (coalesced, L2-resident)
            const __hip_bfloat16* kr = Kph + (size_t)(qi + 4) * 2048 + l31 * 8;
#pragma unroll
            for (int kd = 0; kd < 4; kd++)
                kc[kd] = *reinterpret_cast<const bf16x8*>(kr + (kd * 2 + lg2) * 256);
        }

        if (kvbase == q0) {  // diagonal subtile: causal mask
#pragma unroll
            for (int j = 0; j < 16; j++) {
                int kvl = (j & 3) + 8 * (j >> 2) + 4 * lg2;
                if (kvl > l31) st[j] = -3.0e38f;
            }
        }
        // ---- online softmax (per-lane q=l31; halves merged via shfl 32) ----
        float tm[16];
#pragma unroll
        for (int j = 0; j < 16; j++) tm[j] = st[j];
#pragma unroll
        for (int dd = 8; dd >= 1; dd >>= 1)
#pragma unroll
            for (int j = 0; j < 8; j++)
                if (j < dd) tm[j] = fmaxf(tm[j], tm[j + dd]);
        float mx = fmaxf(tm[0], __shfl_xor(tm[0], 32, 64));
        bool small = __all(mx <= m + 44.0f);  // T13 defer-max
        float mnew = small ? m : fmaxf(m, mx);
#pragma unroll
        for (int j = 0; j < 16; j++)
            st[j] = __builtin_amdgcn_exp2f((st[j] - mnew) * KS2);
        float ts[16];
#pragma unroll
        for (int j = 0; j < 16; j++) ts[j] = st[j];
#pragma unroll
        for (int dd = 8; dd >= 1; dd >>= 1)
#pragma unroll
            for (int j = 0; j < 8; j++)
                if (j < dd) ts[j] += ts[j + dd];
        float ls = ts[0] + __shfl_xor(ts[0], 32, 64);
        if (small) {
            l += ls;
        } else {
            float sc = __builtin_amdgcn_exp2f((m - mnew) * KS2);
            l = l * sc + ls;
            o0 *= sc;
            o1 *= sc;
            m = mnew;
        }

        // ---- in-register P repack (4 shfl) + PV ----
#pragma unroll
        for (int ks = 0; ks < 2; ks++) {
            unsigned int a0 = pack_bf16(st[8 * ks + 0], st[8 * ks + 1]);
            unsigned int a1 = pack_bf16(st[8 * ks + 2], st[8 * ks + 3]);
            unsigned int b0 = pack_bf16(st[8 * ks + 4], st[8 * ks + 5]);
            unsigned int b1 = pack_bf16(st[8 * ks + 6], st[8 * ks + 7]);
            unsigned int y0 = lg2 ? a0 : b0;
            unsigned int y1 = lg2 ? a1 : b1;
            unsigned int p0 = __shfl_xor(y0, 32, 64);
            unsigned int p1 = __shfl_xor(y1, 32, 64);
            union { unsigned int u[4]; bf16x8 v; } pf;
            pf.u[0] = lg2 ? p0 : a0;
            pf.u[1] = lg2 ? p1 : a1;
            pf.u[2] = lg2 ? b0 : p0;
            pf.u[3] = lg2 ? b1 : p1;
            __builtin_amdgcn_s_setprio(1);
            o0 = mfma32(vf[ks * 2 + 0], pf.v, o0);
            o1 = mfma32(vf[ks * 2 + 1], pf.v, o1);
            __builtin_amdgcn_s_setprio(0);
        }
    }

    __syncthreads();  // waves done before combine staging

    // ---- 4-way combine: waves 1..3 stage (o,m,l); wave 0 merges ----
    if (w != 0) {
        float* SCw = (float*)(smem + (w - 1) * 8448);
#pragma unroll
        for (int j = 0; j < 16; j++) {
            int dl = (j & 3) + 8 * (j >> 2) + 4 * lg2;
            SCw[dl * 32 + l31] = o0[j];
            SCw[(32 + dl) * 32 + l31] = o1[j];
        }
        if (lg2 == 0) {
            SCw[2048 + l31] = m;
            SCw[2048 + 32 + l31] = l;
        }
    }
    __syncthreads();
    if (w == 0) {
        float* SC1 = (float*)(smem + 0);
        float* SC2 = (float*)(smem + 8448);
        float* SC3 = (float*)(smem + 16896);
        __hip_bfloat16* OL = (__hip_bfloat16*)(smem + 25344);
        float m1 = SC1[2048 + l31], l1 = SC1[2048 + 32 + l31];
        float m2 = SC2[2048 + l31], l2 = SC2[2048 + 32 + l31];
        float m3 = SC3[2048 + l31], l3 = SC3[2048 + 32 + l31];
        float M = fmaxf(fmaxf(m, m1), fmaxf(m2, m3));
        float e0 = __builtin_amdgcn_exp2f((m - M) * KS2);
        float e1 = __builtin_amdgcn_exp2f((m1 - M) * KS2);
        float e2 = __builtin_amdgcn_exp2f((m2 - M) * KS2);
        float e3 = __builtin_amdgcn_exp2f((m3 - M) * KS2);
        float L = l * e0 + l1 * e1 + l2 * e2 + l3 * e3;
        float linv = 1.0f / L;
#pragma unroll
        for (int od = 0; od < 2; od++) {
#pragma unroll
            for (int g = 0; g < 4; g++) {
                int dbase = od * 32 + 8 * g + 4 * lg2;
                ushort4 w4;
#pragma unroll
                for (int r = 0; r < 4; r++) {
                    int d = dbase + r;
                    float self = od ? o1[4 * g + r] : o0[4 * g + r];
                    float v = self * e0 + SC1[d * 32 + l31] * e1 +
                              SC2[d * 32 + l31] * e2 + SC3[d * 32 + l31] * e3;
                    v *= linv;
                    ((unsigned short*)&w4)[r] = f2bf_bits(v);
                }
                *reinterpret_cast<ushort4*>(&OL[l31 * 72 + dbase]) = w4;
            }
        }
    }
    __syncthreads();
    // coalesced store into QKV K-column hole: O[token][h*64+c] at stride QKVD
    {
        __hip_bfloat16* OL = (__hip_bfloat16*)(smem + 25344);
        int r = tid >> 3, c = (tid & 7) * 8;
        __hip_bfloat16* dst = obase + (size_t)(bbase + q0 + r) * QKVD + h * HDIM + c;
        *reinterpret_cast<uint4*>(dst) = *reinterpret_cast<const uint4*>(&OL[r * 72 + c]);
    }
}

// ---------------- launch ----------------

extern "C" void kernel_launch(void* const* d_in, const int* in_sizes, int n_in,
                              void* d_out, int out_size, void* d_ws, size_t ws_size,
                              hipStream_t stream) {
    const float* hidden = (const float*)d_in[0];   // [2,2048,768]
    const float* w_attn = (const float*)d_in[1];   // [768,2304]
    const float* b_attn = (const float*)d_in[2];   // [2304]
    const float* w_proj = (const float*)d_in[3];   // [768,768]
    const float* b_proj = (const float*)d_in[4];   // [768]
    float* out = (float*)d_out;                    // [2,2048,768]

    char* ws = (char*)d_ws;
    __hip_bfloat16* Xb  = (__hip_bfloat16*)(ws + 0);         // 4096*768*2 = 6291456
    __hip_bfloat16* Wta = (__hip_bfloat16*)(ws + 6291456);   // 2304*768*2
    __hip_bfloat16* Wtp = (__hip_bfloat16*)(ws + 9830400);   // 768*768*2
    __hip_bfloat16* QKV = (__hip_bfloat16*)(ws + 11010048);  // 4096*2304*2
    // packed fragments (after their sources are dead):
    __hip_bfloat16* Kpb = (__hip_bfloat16*)(ws + 0);         // aliases Xb: 24*131072*2 = 6291456
    __hip_bfloat16* Vpb = (__hip_bfloat16*)(ws + 29884416);  // old AO region: 6291456

    const int M = BATCH * SEQ;  // 4096

    f32_to_bf16_k<<<dim3(M * DMODEL / (256 * 4)), dim3(256), 0, stream>>>(hidden, Xb);
    transpose_f32_to_bf16<<<dim3(QKVD / 32, DMODEL / 32), dim3(256), 0, stream>>>(w_attn, Wta, DMODEL, QKVD);
    transpose_f32_to_bf16<<<dim3(DMODEL / 32, DMODEL / 32), dim3(256), 0, stream>>>(w_proj, Wtp, DMODEL, DMODEL);
    gemm_bt<true><<<dim3(QKVD / 128, M / 128), dim3(256), 0, stream>>>(Xb, Wta, b_attn, QKV, M, QKVD, DMODEL, DMODEL);
    pack_kv<<<dim3(SEQ / 32, BATCH * NHEAD), dim3(256), 0, stream>>>(QKV, Kpb, Vpb);
    // flash writes O into QKV's (dead) K columns: obase = QKV + DMODEL, row stride QKVD
    flash_attn<<<dim3(1536), dim3(256), 0, stream>>>(QKV, Kpb, Vpb, QKV + DMODEL);
    gemm_bt<false><<<dim3(DMODEL / 128, M / 128), dim3(256), 0, stream>>>(QKV + DMODEL, Wtp, b_proj, out, M, DMODEL, DMODEL, QKVD);
}